// Round 1
// baseline (382.224 us; speedup 1.0000x reference)
//
#include <hip/hip_runtime.h>
#include <hip/hip_bf16.h>

typedef __bf16 bf16x8 __attribute__((ext_vector_type(8)));
typedef float  f32x4  __attribute__((ext_vector_type(4)));

#define M_DIM 8192
#define N_DIM 4096
#define K_DIM 4096
#define NG    32
#define KHALF (K_DIM / 2)

// ---------------- prep: A fp32 -> bf16 (vectorized, 8 elems/thread/iter) ---
__global__ __launch_bounds__(256) void cvtA_kernel(const float* __restrict__ A,
                                                   __bf16* __restrict__ Ab,
                                                   long n8) {
    long i = (long)blockIdx.x * blockDim.x + threadIdx.x;
    long stride = (long)gridDim.x * blockDim.x;
    const float4* A4 = (const float4*)A;
    for (long p = i; p < n8; p += stride) {
        float4 v0 = A4[2 * p];
        float4 v1 = A4[2 * p + 1];
        bf16x8 o;
        o[0] = (__bf16)v0.x; o[1] = (__bf16)v0.y;
        o[2] = (__bf16)v0.z; o[3] = (__bf16)v0.w;
        o[4] = (__bf16)v1.x; o[5] = (__bf16)v1.y;
        o[6] = (__bf16)v1.z; o[7] = (__bf16)v1.w;
        *(bf16x8*)(Ab + p * 8) = o;
    }
}

// ---------------- prep: unpack int4 + dequant -> W bf16 [N, K] -------------
// qweight [N, K/2] int32, one storage byte per entry (2 nibbles, interleaved:
// col 2i = low nibble, col 2i+1 = high nibble). 4 int32 per thread-chunk ->
// 8 bf16 outputs; a chunk never crosses a GROUP=128 boundary (64 int32/group).
__global__ __launch_bounds__(256) void deqW_kernel(const int* __restrict__ qw,
                                                   const float* __restrict__ sc,
                                                   const float* __restrict__ zr,
                                                   __bf16* __restrict__ Wb) {
    long i = (long)blockIdx.x * blockDim.x + threadIdx.x;
    long stride = (long)gridDim.x * blockDim.x;
    const long nch = (long)N_DIM * (KHALF / 4);   // chunks of 4 int32
    const int4* q4 = (const int4*)qw;
    for (long p = i; p < nch; p += stride) {
        int n  = (int)(p >> 9);      // KHALF/4 = 512 chunks per row
        int cj = (int)(p & 511);
        int i0 = cj * 4;             // int32 index within row
        int g  = i0 >> 6;            // group = (i0*2)/128
        float s = sc[n * NG + g];
        float z = zr[n * NG + g];
        int4 qv = q4[p];
        bf16x8 o;
        int b;
        b = qv.x; o[0] = (__bf16)(((float)(b & 0xF) - z) * s);
                  o[1] = (__bf16)(((float)((b >> 4) & 0xF) - z) * s);
        b = qv.y; o[2] = (__bf16)(((float)(b & 0xF) - z) * s);
                  o[3] = (__bf16)(((float)((b >> 4) & 0xF) - z) * s);
        b = qv.z; o[4] = (__bf16)(((float)(b & 0xF) - z) * s);
                  o[5] = (__bf16)(((float)((b >> 4) & 0xF) - z) * s);
        b = qv.w; o[6] = (__bf16)(((float)(b & 0xF) - z) * s);
                  o[7] = (__bf16)(((float)((b >> 4) & 0xF) - z) * s);
        *(bf16x8*)(Wb + (long)n * K_DIM + i0 * 2) = o;
    }
}

// ---------------- main GEMM: C = A(bf16) * B(bf16)^T, m97 structure --------
// 128x128 tile, BK=64, 4 waves (2x2), each wave 64x64 out = 4x4 frags of
// 16x16x32 MFMA. global_load_lds width 16, linear LDS [rows][64] bf16.
#define BM 128
#define BN 128
#define BK 64

__global__ __launch_bounds__(256, 3) void gemm_kernel(const __bf16* __restrict__ A,
                                                      const __bf16* __restrict__ B,
                                                      float* __restrict__ C) {
    __shared__ __bf16 As[BM * BK];   // 16 KiB
    __shared__ __bf16 Bs[BN * BK];   // 16 KiB

    // XCD-aware swizzle (nwg = 2048, divisible by 8 -> bijective)
    const int nwg = (M_DIM / BM) * (N_DIM / BN);
    const int cpx = nwg >> 3;
    int bid = blockIdx.x;
    int sw  = (bid & 7) * cpx + (bid >> 3);
    const int ntn = N_DIM / BN;      // 32
    int mt = sw / ntn, nt = sw % ntn;
    int bm0 = mt * BM, bn0 = nt * BN;

    int tid  = threadIdx.x;
    int lane = tid & 63;
    int wid  = tid >> 6;
    int wr   = wid >> 1, wc = wid & 1;

    f32x4 acc[4][4];
    f32x4 vzero = {0.f, 0.f, 0.f, 0.f};
#pragma unroll
    for (int m = 0; m < 4; ++m)
#pragma unroll
        for (int n = 0; n < 4; ++n)
            acc[m][n] = vzero;

    // staging: round q, thread t -> row q*32 + t/8, col (t%8)*8 (elements);
    // LDS dest byte = q*4096 + t*16 (wave-uniform base + lane*16: OK)
    int srow = tid >> 3;
    int scol = (tid & 7) * 8;
    const __bf16* Ag = A + (long)(bm0 + srow) * K_DIM + scol;
    const __bf16* Bg = B + (long)(bn0 + srow) * K_DIM + scol;
    char* AsB = (char*)As;
    char* BsB = (char*)Bs;
    int ldst = tid * 16;

    // fragment read: lane -> row (lane&15), k-chunk (lane>>4)*8
    int fr = lane & 15;
    int fk = (lane >> 4) * 8;

    for (int k0 = 0; k0 < K_DIM; k0 += BK) {
        __syncthreads();   // previous tile fully consumed
#pragma unroll
        for (int q = 0; q < 4; ++q)
            __builtin_amdgcn_global_load_lds(
                (__attribute__((address_space(1))) void*)(Ag + (long)q * 32 * K_DIM + k0),
                (__attribute__((address_space(3))) void*)(AsB + q * 4096 + ldst),
                16, 0, 0);
#pragma unroll
        for (int q = 0; q < 4; ++q)
            __builtin_amdgcn_global_load_lds(
                (__attribute__((address_space(1))) void*)(Bg + (long)q * 32 * K_DIM + k0),
                (__attribute__((address_space(3))) void*)(BsB + q * 4096 + ldst),
                16, 0, 0);
        __syncthreads();   // compiler drains vmcnt before barrier

#pragma unroll
        for (int kk = 0; kk < 2; ++kk) {
            bf16x8 af[4], bfr[4];
#pragma unroll
            for (int m = 0; m < 4; ++m)
                af[m] = *(const bf16x8*)(As + (wr * 64 + m * 16 + fr) * BK + kk * 32 + fk);
#pragma unroll
            for (int n = 0; n < 4; ++n)
                bfr[n] = *(const bf16x8*)(Bs + (wc * 64 + n * 16 + fr) * BK + kk * 32 + fk);
#pragma unroll
            for (int m = 0; m < 4; ++m)
#pragma unroll
                for (int n = 0; n < 4; ++n)
                    acc[m][n] = __builtin_amdgcn_mfma_f32_16x16x32_bf16(
                        af[m], bfr[n], acc[m][n], 0, 0, 0);
        }
    }

    // epilogue: C/D layout col = lane&15, row = (lane>>4)*4 + j  [m89/m91]
    int crow0 = bm0 + wr * 64 + (lane >> 4) * 4;
    int ccol0 = bn0 + wc * 64 + (lane & 15);
#pragma unroll
    for (int m = 0; m < 4; ++m)
#pragma unroll
        for (int n = 0; n < 4; ++n) {
            long base = (long)(crow0 + m * 16) * N_DIM + (ccol0 + n * 16);
#pragma unroll
            for (int j = 0; j < 4; ++j)
                C[base + (long)j * N_DIM] = acc[m][n][j];
        }
}

// ---------------- fallback (only if ws_size < 96 MiB): fused naive ---------
__global__ __launch_bounds__(256) void gemm_fallback(const float* __restrict__ A,
                                                     const int* __restrict__ qw,
                                                     const float* __restrict__ sc,
                                                     const float* __restrict__ zr,
                                                     float* __restrict__ C) {
    __shared__ float Ash[16][17];
    __shared__ float Wsh[16][17];
    int tx = threadIdx.x & 15, ty = threadIdx.x >> 4;
    int m = blockIdx.y * 16 + ty;
    int n = blockIdx.x * 16 + tx;
    float s = 0.f;
    for (int k0 = 0; k0 < K_DIM; k0 += 16) {
        Ash[ty][tx] = A[(long)m * K_DIM + k0 + tx];
        {
            int nn = blockIdx.x * 16 + ty;
            int kk = k0 + tx;
            int q = qw[(long)nn * KHALF + (kk >> 1)];
            int nib = (kk & 1) ? ((q >> 4) & 0xF) : (q & 0xF);
            int g = kk >> 7;
            Wsh[ty][tx] = ((float)nib - zr[nn * NG + g]) * sc[nn * NG + g];
        }
        __syncthreads();
#pragma unroll
        for (int kk = 0; kk < 16; ++kk)
            s += Ash[ty][kk] * Wsh[tx][kk];
        __syncthreads();
    }
    C[(long)m * N_DIM + n] = s;
}

extern "C" void kernel_launch(void* const* d_in, const int* in_sizes, int n_in,
                              void* d_out, int out_size, void* d_ws, size_t ws_size,
                              hipStream_t stream) {
    const float* A  = (const float*)d_in[0];
    const int*   qw = (const int*)d_in[1];
    const float* sc = (const float*)d_in[2];
    const float* zr = (const float*)d_in[3];
    float* C = (float*)d_out;

    const size_t needA = (size_t)M_DIM * K_DIM * 2;   // 64 MiB
    const size_t needW = (size_t)N_DIM * K_DIM * 2;   // 32 MiB

    if (ws_size >= needA + needW) {
        __bf16* Ab = (__bf16*)d_ws;
        __bf16* Wb = (__bf16*)((char*)d_ws + needA);
        cvtA_kernel<<<2048, 256, 0, stream>>>(A, Ab, (long)M_DIM * K_DIM / 8);
        deqW_kernel<<<2048, 256, 0, stream>>>(qw, sc, zr, Wb);
        gemm_kernel<<<2048, 256, 0, stream>>>(Ab, Wb, C);
    } else {
        dim3 g(N_DIM / 16, M_DIM / 16);
        gemm_fallback<<<g, 256, 0, stream>>>(A, qw, sc, zr, C);
    }
}

// Round 2
// 287.224 us; speedup vs baseline: 1.3308x; 1.3308x over previous
//
#include <hip/hip_runtime.h>
#include <hip/hip_bf16.h>

typedef __bf16 bf16x8 __attribute__((ext_vector_type(8)));
typedef float  f32x4  __attribute__((ext_vector_type(4)));

#define M_DIM 8192
#define N_DIM 4096
#define K_DIM 4096
#define NG    32
#define KHALF (K_DIM / 2)

// ---------------- prep: A fp32 -> bf16 (vectorized) ------------------------
__global__ __launch_bounds__(256) void cvtA_kernel(const float* __restrict__ A,
                                                   __bf16* __restrict__ Ab,
                                                   long n8) {
    long i = (long)blockIdx.x * blockDim.x + threadIdx.x;
    long stride = (long)gridDim.x * blockDim.x;
    const float4* A4 = (const float4*)A;
    for (long p = i; p < n8; p += stride) {
        float4 v0 = A4[2 * p];
        float4 v1 = A4[2 * p + 1];
        bf16x8 o;
        o[0] = (__bf16)v0.x; o[1] = (__bf16)v0.y;
        o[2] = (__bf16)v0.z; o[3] = (__bf16)v0.w;
        o[4] = (__bf16)v1.x; o[5] = (__bf16)v1.y;
        o[6] = (__bf16)v1.z; o[7] = (__bf16)v1.w;
        *(bf16x8*)(Ab + p * 8) = o;
    }
}

// ---------------- prep: unpack int4 + dequant -> W bf16 [N, K] -------------
__global__ __launch_bounds__(256) void deqW_kernel(const int* __restrict__ qw,
                                                   const float* __restrict__ sc,
                                                   const float* __restrict__ zr,
                                                   __bf16* __restrict__ Wb) {
    long i = (long)blockIdx.x * blockDim.x + threadIdx.x;
    long stride = (long)gridDim.x * blockDim.x;
    const long nch = (long)N_DIM * (KHALF / 4);
    const int4* q4 = (const int4*)qw;
    for (long p = i; p < nch; p += stride) {
        int n  = (int)(p >> 9);
        int cj = (int)(p & 511);
        int i0 = cj * 4;
        int g  = i0 >> 6;
        float s = sc[n * NG + g];
        float z = zr[n * NG + g];
        int4 qv = q4[p];
        bf16x8 o;
        int b;
        b = qv.x; o[0] = (__bf16)(((float)(b & 0xF) - z) * s);
                  o[1] = (__bf16)(((float)((b >> 4) & 0xF) - z) * s);
        b = qv.y; o[2] = (__bf16)(((float)(b & 0xF) - z) * s);
                  o[3] = (__bf16)(((float)((b >> 4) & 0xF) - z) * s);
        b = qv.z; o[4] = (__bf16)(((float)(b & 0xF) - z) * s);
                  o[5] = (__bf16)(((float)((b >> 4) & 0xF) - z) * s);
        b = qv.w; o[6] = (__bf16)(((float)(b & 0xF) - z) * s);
                  o[7] = (__bf16)(((float)((b >> 4) & 0xF) - z) * s);
        *(bf16x8*)(Wb + (long)n * K_DIM + i0 * 2) = o;
    }
}

// ---------------- main GEMM: 256x256 tile, BK=64, 8-wave, 8-phase ----------
// LDS 128 KiB: [dbuf 2][mat A/B][half 2][128 rows x 64 cols bf16 = 16 KiB]
// T2 swizzle: lds byte (row, colb) stored at colb ^ ((row&7)<<4); applied via
// inverse-swizzled GLOBAL source (linear global_load_lds dest) + swizzled read.
#define BM 256
#define BN 256
#define BK 64
#define NT (K_DIM / BK)   // 64

#define BAR   __builtin_amdgcn_s_barrier()
#define LGKM0 asm volatile("s_waitcnt lgkmcnt(0)" ::: "memory")

// stage one half-tile (2 x global_load_lds dwordx4): SRC = per-thread swizzled
// global base (row srow, swizzled col), H = half, DB = dbuf byte base, KT = k-tile
#define STAGE(SRC, MATOFF, H, DB, KT)                                                              \
  do {                                                                                             \
    __builtin_amdgcn_global_load_lds(                                                              \
        (__attribute__((address_space(1))) void*)((SRC) + (long)((H) * 128) * (K_DIM * 2) +        \
                                                  (long)(KT) * (BK * 2)),                          \
        (__attribute__((address_space(3))) void*)(lds + (DB) + (MATOFF) + (H) * 16384 + ldst),     \
        16, 0, 0);                                                                                 \
    __builtin_amdgcn_global_load_lds(                                                              \
        (__attribute__((address_space(1))) void*)((SRC) + (long)((H) * 128 + 64) * (K_DIM * 2) +   \
                                                  (long)(KT) * (BK * 2)),                          \
        (__attribute__((address_space(3))) void*)(lds + (DB) + (MATOFF) + (H) * 16384 + 8192 +     \
                                                  ldst),                                           \
        16, 0, 0);                                                                                 \
  } while (0)

#define READ_A(QM, DB)                                                                             \
  do {                                                                                             \
    _Pragma("unroll") for (int m_ = 0; m_ < 4; ++m_) {                                             \
      areg[m_][0] = *(const bf16x8*)(lds + (DB) + aoff + ((QM) * 64 + m_ * 16) * 128 + rc0);       \
      areg[m_][1] = *(const bf16x8*)(lds + (DB) + aoff + ((QM) * 64 + m_ * 16) * 128 + rc1);       \
    }                                                                                              \
  } while (0)

#define READ_B(QN, DB)                                                                             \
  do {                                                                                             \
    _Pragma("unroll") for (int n_ = 0; n_ < 2; ++n_) {                                             \
      breg[QN][n_][0] = *(const bf16x8*)(lds + (DB) + boff + ((QN) * 32 + n_ * 16) * 128 + rc0);   \
      breg[QN][n_][1] = *(const bf16x8*)(lds + (DB) + boff + ((QN) * 32 + n_ * 16) * 128 + rc1);   \
    }                                                                                              \
  } while (0)

#define QUAD(QM, QN)                                                                               \
  do {                                                                                             \
    __builtin_amdgcn_s_setprio(1);                                                                 \
    _Pragma("unroll") for (int m_ = 0; m_ < 4; ++m_)                                               \
      _Pragma("unroll") for (int n_ = 0; n_ < 2; ++n_) {                                           \
        acc[(QM) * 4 + m_][(QN) * 2 + n_] = __builtin_amdgcn_mfma_f32_16x16x32_bf16(               \
            areg[m_][0], breg[QN][n_][0], acc[(QM) * 4 + m_][(QN) * 2 + n_], 0, 0, 0);             \
        acc[(QM) * 4 + m_][(QN) * 2 + n_] = __builtin_amdgcn_mfma_f32_16x16x32_bf16(               \
            areg[m_][1], breg[QN][n_][1], acc[(QM) * 4 + m_][(QN) * 2 + n_], 0, 0, 0);             \
      }                                                                                            \
    __builtin_amdgcn_s_setprio(0);                                                                 \
  } while (0)

__global__ __launch_bounds__(512, 2) void gemm8p(const __bf16* __restrict__ A,
                                                 const __bf16* __restrict__ B,
                                                 float* __restrict__ C) {
    __shared__ __attribute__((aligned(128))) char lds[131072];

    // XCD-aware bijective swizzle: nwg = 512, divisible by 8
    const int nwg = (M_DIM / BM) * (N_DIM / BN);   // 512
    int bid = blockIdx.x;
    int sw  = (bid & 7) * (nwg >> 3) + (bid >> 3);
    int mt = sw >> 4, ntl = sw & 15;               // 32 x 16 tiles
    int bm0 = mt * BM, bn0 = ntl * BN;

    int tid  = threadIdx.x;
    int lane = tid & 63;
    int wid  = tid >> 6;
    int wr   = wid >> 2;      // 0..1  (M half)
    int wc   = wid & 3;       // 0..3  (N quarter)

    f32x4 acc[8][4];
    f32x4 vz = {0.f, 0.f, 0.f, 0.f};
#pragma unroll
    for (int m = 0; m < 8; ++m)
#pragma unroll
        for (int n = 0; n < 4; ++n) acc[m][n] = vz;

    bf16x8 areg[4][2];
    bf16x8 breg[2][2][2];

    // ---- staging addressing (inverse-swizzled global source, linear dest) ----
    int srow  = tid >> 3;                                  // 0..63 within a 64-row load
    int scolb = ((tid & 7) ^ (srow & 7)) * 16;             // swizzled 16B slot
    const char* Asrc = (const char*)(A + (long)(bm0 + srow) * K_DIM) + scolb;
    const char* Bsrc = (const char*)(B + (long)(bn0 + srow) * K_DIM) + scolb;
    int ldst = tid * 16;                                   // linear LDS dest

    // ---- fragment-read addressing (swizzled) ----
    int lrow = lane & 15;
    int rdc  = (((lane >> 4) ^ (lane & 7)) << 4);          // swizzled col, kk=0
    int rc0  = rdc;
    int rc1  = rdc ^ 64;                                   // kk=1
    int aoff = wr * 16384 + lrow * 128;                    // A matOff = 0
    int boff = 32768 + (wc >> 1) * 16384 + ((wc & 1) * 64 + lrow) * 128;

    // ---- prologue: tile0 (A0,A1,B0,B1)->dbuf0; tile1 (B0,A0,A1)->dbuf1 ----
    STAGE(Asrc, 0,     0, 0, 0);
    STAGE(Asrc, 0,     1, 0, 0);
    STAGE(Bsrc, 32768, 0, 0, 0);
    STAGE(Bsrc, 32768, 1, 0, 0);
    STAGE(Bsrc, 32768, 0, 65536, 1);
    STAGE(Asrc, 0,     0, 65536, 1);
    STAGE(Asrc, 0,     1, 65536, 1);
    asm volatile("s_waitcnt vmcnt(6)" ::: "memory");       // tile0 landed, 3 ht in flight
    BAR;

    for (int kt = 0; kt < NT; ++kt) {
        int dB = (kt & 1) << 16;
        int nB = dB ^ 65536;

        // ---- phase 1: quadrant (0,0); 12 ds_reads; stage (kt+1) B1 ----
        READ_A(0, dB);
        READ_B(0, dB);
        if (kt + 1 < NT) STAGE(Bsrc, 32768, 1, nB, kt + 1);
        asm volatile("s_waitcnt lgkmcnt(8)" ::: "memory");
        BAR;
        LGKM0;
        QUAD(0, 0);
        BAR;

        // ---- phase 2: quadrant (0,1); 4 ds_reads ----
        READ_B(1, dB);
        BAR;
        LGKM0;
        QUAD(0, 1);
        BAR;

        // ---- phase 3: quadrant (1,0); 8 ds_reads; stage (kt+2) B0 ----
        // (tile kt's B0 region fully consumed after phase 2)
        READ_A(1, dB);
        if (kt + 2 < NT) STAGE(Bsrc, 32768, 0, dB, kt + 2);
        BAR;
        LGKM0;
        QUAD(1, 0);
        BAR;

        // ---- phase 4: quadrant (1,1); 0 ds_reads; stage (kt+2) A0,A1 ----
        // (tile kt's A regions fully consumed after phase 3)
        if (kt + 2 < NT) {
            STAGE(Asrc, 0, 0, dB, kt + 2);
            STAGE(Asrc, 0, 1, dB, kt + 2);
        }
        if (kt < NT - 2) {
            asm volatile("s_waitcnt vmcnt(6)" ::: "memory");   // counted, never 0 mid-loop
        } else {
            asm volatile("s_waitcnt vmcnt(0)" ::: "memory");   // tail drain
        }
        BAR;
        QUAD(1, 1);
        BAR;
    }

    // ---- epilogue: C/D layout col = lane&15, row = (lane>>4)*4 + j ----
    int crow0 = bm0 + wr * 128 + (lane >> 4) * 4;
    int ccol0 = bn0 + wc * 64 + (lane & 15);
#pragma unroll
    for (int m = 0; m < 8; ++m)
#pragma unroll
        for (int n = 0; n < 4; ++n) {
            long base = (long)(crow0 + m * 16) * N_DIM + (ccol0 + n * 16);
#pragma unroll
            for (int j = 0; j < 4; ++j)
                C[base + (long)j * N_DIM] = acc[m][n][j];
        }
}

// ---------------- fallback (only if ws too small): fused naive -------------
__global__ __launch_bounds__(256) void gemm_fallback(const float* __restrict__ A,
                                                     const int* __restrict__ qw,
                                                     const float* __restrict__ sc,
                                                     const float* __restrict__ zr,
                                                     float* __restrict__ C) {
    __shared__ float Ash[16][17];
    __shared__ float Wsh[16][17];
    int tx = threadIdx.x & 15, ty = threadIdx.x >> 4;
    int m = blockIdx.y * 16 + ty;
    int n = blockIdx.x * 16 + tx;
    float s = 0.f;
    for (int k0 = 0; k0 < K_DIM; k0 += 16) {
        Ash[ty][tx] = A[(long)m * K_DIM + k0 + tx];
        {
            int nn = blockIdx.x * 16 + ty;
            int kk = k0 + tx;
            int q = qw[(long)nn * KHALF + (kk >> 1)];
            int nib = (kk & 1) ? ((q >> 4) & 0xF) : (q & 0xF);
            int g = kk >> 7;
            Wsh[ty][tx] = ((float)nib - zr[nn * NG + g]) * sc[nn * NG + g];
        }
        __syncthreads();
#pragma unroll
        for (int kk = 0; kk < 16; ++kk)
            s += Ash[ty][kk] * Wsh[tx][kk];
        __syncthreads();
    }
    C[(long)m * N_DIM + n] = s;
}

extern "C" void kernel_launch(void* const* d_in, const int* in_sizes, int n_in,
                              void* d_out, int out_size, void* d_ws, size_t ws_size,
                              hipStream_t stream) {
    const float* A  = (const float*)d_in[0];
    const int*   qw = (const int*)d_in[1];
    const float* sc = (const float*)d_in[2];
    const float* zr = (const float*)d_in[3];
    float* C = (float*)d_out;

    const size_t needA = (size_t)M_DIM * K_DIM * 2;   // 64 MiB
    const size_t needW = (size_t)N_DIM * K_DIM * 2;   // 32 MiB

    if (ws_size >= needA + needW) {
        __bf16* Ab = (__bf16*)d_ws;
        __bf16* Wb = (__bf16*)((char*)d_ws + needA);
        cvtA_kernel<<<2048, 256, 0, stream>>>(A, Ab, (long)M_DIM * K_DIM / 8);
        deqW_kernel<<<2048, 256, 0, stream>>>(qw, sc, zr, Wb);
        gemm8p<<<(M_DIM / BM) * (N_DIM / BN), 512, 0, stream>>>(Ab, Wb, C);
    } else {
        dim3 g(N_DIM / 16, M_DIM / 16);
        gemm_fallback<<<g, 256, 0, stream>>>(A, qw, sc, zr, C);
    }
}

// Round 3
// 277.163 us; speedup vs baseline: 1.3791x; 1.0363x over previous
//
#include <hip/hip_runtime.h>
#include <hip/hip_bf16.h>

typedef __bf16 bf16x8 __attribute__((ext_vector_type(8)));
typedef float  f32x4  __attribute__((ext_vector_type(4)));
typedef __attribute__((address_space(3))) char* lds3_t;

#define M_DIM 8192
#define N_DIM 4096
#define K_DIM 4096
#define NG    32
#define KHALF (K_DIM / 2)

// ---------------- prep: A fp32 -> bf16 (vectorized) ------------------------
__global__ __launch_bounds__(256) void cvtA_kernel(const float* __restrict__ A,
                                                   __bf16* __restrict__ Ab,
                                                   long n8) {
    long i = (long)blockIdx.x * blockDim.x + threadIdx.x;
    long stride = (long)gridDim.x * blockDim.x;
    const float4* A4 = (const float4*)A;
    for (long p = i; p < n8; p += stride) {
        float4 v0 = A4[2 * p];
        float4 v1 = A4[2 * p + 1];
        bf16x8 o;
        o[0] = (__bf16)v0.x; o[1] = (__bf16)v0.y;
        o[2] = (__bf16)v0.z; o[3] = (__bf16)v0.w;
        o[4] = (__bf16)v1.x; o[5] = (__bf16)v1.y;
        o[6] = (__bf16)v1.z; o[7] = (__bf16)v1.w;
        *(bf16x8*)(Ab + p * 8) = o;
    }
}

// ---------------- prep: unpack int4 + dequant -> W bf16 [N, K] -------------
__global__ __launch_bounds__(256) void deqW_kernel(const int* __restrict__ qw,
                                                   const float* __restrict__ sc,
                                                   const float* __restrict__ zr,
                                                   __bf16* __restrict__ Wb) {
    long i = (long)blockIdx.x * blockDim.x + threadIdx.x;
    long stride = (long)gridDim.x * blockDim.x;
    const long nch = (long)N_DIM * (KHALF / 4);
    const int4* q4 = (const int4*)qw;
    for (long p = i; p < nch; p += stride) {
        int n  = (int)(p >> 9);
        int cj = (int)(p & 511);
        int i0 = cj * 4;
        int g  = i0 >> 6;
        float s = sc[n * NG + g];
        float z = zr[n * NG + g];
        int4 qv = q4[p];
        bf16x8 o;
        int b;
        b = qv.x; o[0] = (__bf16)(((float)(b & 0xF) - z) * s);
                  o[1] = (__bf16)(((float)((b >> 4) & 0xF) - z) * s);
        b = qv.y; o[2] = (__bf16)(((float)(b & 0xF) - z) * s);
                  o[3] = (__bf16)(((float)((b >> 4) & 0xF) - z) * s);
        b = qv.z; o[4] = (__bf16)(((float)(b & 0xF) - z) * s);
                  o[5] = (__bf16)(((float)((b >> 4) & 0xF) - z) * s);
        b = qv.w; o[6] = (__bf16)(((float)(b & 0xF) - z) * s);
                  o[7] = (__bf16)(((float)((b >> 4) & 0xF) - z) * s);
        *(bf16x8*)(Wb + (long)n * K_DIM + i0 * 2) = o;
    }
}

// ---------------- main GEMM: 256x256, BK=64, 8-wave, 8-subphase snake ------
// Per K-tile: 8 phases at (quadrant,kk) granularity, snake order
// (00,0)(10,0)(11,0)(01,0)(01,1)(11,1)(10,1)(00,1). Each phase issues the
// ds_reads for a LATER phase (inline asm) + counted lgkmcnt so LDS hides
// under MFMA. Stage 1 half-tile in 4 of 8 phases; vmcnt(2) once per tile.
#define BM 256
#define BN 256
#define BK 64
#define NT (K_DIM / BK)   // 64

#define SB0 __builtin_amdgcn_sched_barrier(0)
#define BAR do { SB0; __builtin_amdgcn_s_barrier(); } while (0)
#define LGKM(N) do { asm volatile("s_waitcnt lgkmcnt(" #N ")" ::: "memory"); SB0; } while (0)
#define VMW(N)  do { asm volatile("s_waitcnt vmcnt(" #N ")"  ::: "memory"); SB0; } while (0)
#define PRIO1 __builtin_amdgcn_s_setprio(1)
#define PRIO0 __builtin_amdgcn_s_setprio(0)

#define DSR(dst, base, OFFS) \
    asm volatile("ds_read_b128 %0, %1 offset:" OFFS : "=v"(dst) : "v"(base))

// A quadrant read: 4 x b128. Q/K literal tokens; BASEV = addr variable.
#define RD_A(BASEV, Q, K, O0, O1, O2, O3)          \
  do {                                             \
    DSR(a##Q##k##K[0], BASEV, O0);                 \
    DSR(a##Q##k##K[1], BASEV, O1);                 \
    DSR(a##Q##k##K[2], BASEV, O2);                 \
    DSR(a##Q##k##K[3], BASEV, O3);                 \
  } while (0)

// B quadrant read: 2 x b128.
#define RD_B(BASEV, Q, K, O0, O1)                  \
  do {                                             \
    DSR(b##Q##k##K[0], BASEV, O0);                 \
    DSR(b##Q##k##K[1], BASEV, O1);                 \
  } while (0)

#define ACC1(QM, MM, QN, NN, KK)                                                 \
  acc[(QM) * 4 + (MM)][(QN) * 2 + (NN)] = __builtin_amdgcn_mfma_f32_16x16x32_bf16( \
      a##QM##k##KK[MM], b##QN##k##KK[NN], acc[(QM) * 4 + (MM)][(QN) * 2 + (NN)], 0, 0, 0)

#define MFMA8(QM, QN, KK)       \
  do {                          \
    PRIO1;                      \
    ACC1(QM, 0, QN, 0, KK);     \
    ACC1(QM, 0, QN, 1, KK);     \
    ACC1(QM, 1, QN, 0, KK);     \
    ACC1(QM, 1, QN, 1, KK);     \
    ACC1(QM, 2, QN, 0, KK);     \
    ACC1(QM, 2, QN, 1, KK);     \
    ACC1(QM, 3, QN, 0, KK);     \
    ACC1(QM, 3, QN, 1, KK);     \
    PRIO0;                      \
  } while (0)

// stage one half-tile (2 x global_load_lds dwordx4)
#define STAGE(SRC, MATOFF, H, DB, KT)                                                              \
  do {                                                                                             \
    __builtin_amdgcn_global_load_lds(                                                              \
        (__attribute__((address_space(1))) void*)((SRC) + (long)((H) * 128) * (K_DIM * 2) +        \
                                                  (long)(KT) * (BK * 2)),                          \
        (__attribute__((address_space(3))) void*)(lds + (DB) + (MATOFF) + (H) * 16384 + ldst),     \
        16, 0, 0);                                                                                 \
    __builtin_amdgcn_global_load_lds(                                                              \
        (__attribute__((address_space(1))) void*)((SRC) + (long)((H) * 128 + 64) * (K_DIM * 2) +   \
                                                  (long)(KT) * (BK * 2)),                          \
        (__attribute__((address_space(3))) void*)(lds + (DB) + (MATOFF) + (H) * 16384 + 8192 +     \
                                                  ldst),                                           \
        16, 0, 0);                                                                                 \
  } while (0)

// One K-tile, parity P (literal 0/1), next parity PN. aaP0 etc = addr vars.
#define TILE(P, PN, JJ)                                                           \
  do {                                                                            \
    const int jp1 = (JJ) + 1, jp2 = (JJ) + 2;                                     \
    /* ph1: MFMA(0,0,k0); read A1k0; stage B-h0(j+1) */                           \
    BAR;                                                                          \
    RD_A(aa##P##0, 1, 0, "8192", "10240", "12288", "14336");                      \
    if (jp1 < NT) STAGE(Bsrc, 32768, 0, (PN) * 65536, jp1);                       \
    LGKM(4);                                                                      \
    MFMA8(0, 0, 0);                                                               \
    /* ph2: MFMA(1,0,k0); read B1k0; stage B-h1(j+1) */                           \
    BAR;                                                                          \
    RD_B(ba##P##0, 1, 0, "4096", "6144");                                         \
    if (jp1 < NT) STAGE(Bsrc, 32768, 1, (PN) * 65536, jp1);                       \
    LGKM(2);                                                                      \
    MFMA8(1, 0, 0);                                                               \
    /* ph3: MFMA(1,1,k0) */                                                       \
    BAR;                                                                          \
    LGKM(0);                                                                      \
    MFMA8(1, 1, 0);                                                               \
    /* ph4: MFMA(0,1,k0); read A0k1 + B1k1 */                                     \
    BAR;                                                                          \
    RD_A(aa##P##1, 0, 1, "0", "2048", "4096", "6144");                            \
    RD_B(ba##P##1, 1, 1, "4096", "6144");                                         \
    LGKM(6);                                                                      \
    MFMA8(0, 1, 0);                                                               \
    /* ph5: MFMA(0,1,k1); read A1k1 */                                            \
    BAR;                                                                          \
    RD_A(aa##P##1, 1, 1, "8192", "10240", "12288", "14336");                      \
    LGKM(4);                                                                      \
    MFMA8(0, 1, 1);                                                               \
    /* ph6: MFMA(1,1,k1); read B0k1 */                                            \
    BAR;                                                                          \
    RD_B(ba##P##1, 0, 1, "0", "2048");                                            \
    LGKM(2);                                                                      \
    MFMA8(1, 1, 1);                                                               \
    /* ph7: MFMA(1,0,k1); stage A-h0(j+2); vmcnt */                               \
    BAR;                                                                          \
    LGKM(0);                                                                      \
    if (jp2 < NT) {                                                               \
      STAGE(Asrc, 0, 0, (P) * 65536, jp2);                                        \
      VMW(2);                                                                     \
    } else {                                                                      \
      VMW(0);                                                                     \
    }                                                                             \
    MFMA8(1, 0, 1);                                                               \
    /* ph8: MFMA(0,0,k1); read next-tile A0k0,B0k0 (parity PN); stage A-h1 */     \
    BAR;                                                                          \
    RD_A(aa##PN##0, 0, 0, "0", "2048", "4096", "6144");                           \
    RD_B(ba##PN##0, 0, 0, "0", "2048");                                           \
    if (jp2 < NT) STAGE(Asrc, 0, 1, (P) * 65536, jp2);                            \
    LGKM(6);                                                                      \
    MFMA8(0, 0, 1);                                                               \
  } while (0)

__global__ __launch_bounds__(512, 2) void gemm8p(const __bf16* __restrict__ A,
                                                 const __bf16* __restrict__ B,
                                                 float* __restrict__ C) {
    __shared__ __attribute__((aligned(128))) char lds[131072];

    // XCD-aware bijective swizzle: nwg = 512, divisible by 8
    const int nwg = (M_DIM / BM) * (N_DIM / BN);   // 512
    int bid = blockIdx.x;
    int sw  = (bid & 7) * (nwg >> 3) + (bid >> 3);
    int mt = sw >> 4, ntl = sw & 15;               // 32 x 16 tiles
    int bm0 = mt * BM, bn0 = ntl * BN;

    int tid  = threadIdx.x;
    int lane = tid & 63;
    int wid  = tid >> 6;
    int wr   = wid >> 2;      // 0..1  (M half)
    int wc   = wid & 3;       // 0..3  (N quarter)

    f32x4 acc[8][4];
    f32x4 vz = {0.f, 0.f, 0.f, 0.f};
#pragma unroll
    for (int m = 0; m < 8; ++m)
#pragma unroll
        for (int n = 0; n < 4; ++n) acc[m][n] = vz;

    // fragment registers (single-buffered; snake order makes WAR legal)
    bf16x8 a0k0[4], a1k0[4], a0k1[4], a1k1[4];
    bf16x8 b0k0[2], b1k0[2], b0k1[2], b1k1[2];

    // ---- staging addressing (inverse-swizzled global source, linear dest) ----
    int srow  = tid >> 3;
    int scolb = ((tid & 7) ^ (srow & 7)) * 16;
    const char* Asrc = (const char*)(A + (long)(bm0 + srow) * K_DIM) + scolb;
    const char* Bsrc = (const char*)(B + (long)(bn0 + srow) * K_DIM) + scolb;
    int ldst = tid * 16;

    // ---- fragment-read addressing (swizzled), as addrspace(3) pointers ----
    int lrow = lane & 15;
    int rc0  = (((lane >> 4) ^ (lane & 7)) << 4);
    int rc1  = rc0 ^ 64;
    int aoff = wr * 16384 + lrow * 128;
    int boff = 32768 + (wc >> 1) * 16384 + ((wc & 1) * 64 + lrow) * 128;

    lds3_t aa00 = (lds3_t)(lds + aoff + rc0);
    lds3_t aa01 = (lds3_t)(lds + aoff + rc1);
    lds3_t aa10 = (lds3_t)(lds + 65536 + aoff + rc0);
    lds3_t aa11 = (lds3_t)(lds + 65536 + aoff + rc1);
    lds3_t ba00 = (lds3_t)(lds + boff + rc0);
    lds3_t ba01 = (lds3_t)(lds + boff + rc1);
    lds3_t ba10 = (lds3_t)(lds + 65536 + boff + rc0);
    lds3_t ba11 = (lds3_t)(lds + 65536 + boff + rc1);

    // ---- prologue: stage tile0 (all) + tile1 (A halves); then first reads ----
    STAGE(Asrc, 0,     0, 0, 0);
    STAGE(Asrc, 0,     1, 0, 0);
    STAGE(Bsrc, 32768, 0, 0, 0);
    STAGE(Bsrc, 32768, 1, 0, 0);
    STAGE(Asrc, 0,     0, 65536, 1);
    STAGE(Asrc, 0,     1, 65536, 1);
    VMW(4);                               // tile0 landed; tile1-A in flight
    BAR;
    RD_A(aa00, 0, 0, "0", "2048", "4096", "6144");   // A0k0(0)
    RD_B(ba00, 0, 0, "0", "2048");                   // B0k0(0)

    for (int j = 0; j < NT; j += 2) {
        TILE(0, 1, j);
        TILE(1, 0, j + 1);
    }

    // ---- epilogue: C/D layout col = lane&15, row = (lane>>4)*4 + jj ----
    int crow0 = bm0 + wr * 128 + (lane >> 4) * 4;
    int ccol0 = bn0 + wc * 64 + (lane & 15);
#pragma unroll
    for (int m = 0; m < 8; ++m)
#pragma unroll
        for (int n = 0; n < 4; ++n) {
            long base = (long)(crow0 + m * 16) * N_DIM + (ccol0 + n * 16);
#pragma unroll
            for (int jj = 0; jj < 4; ++jj)
                C[base + (long)jj * N_DIM] = acc[m][n][jj];
        }
}

// ---------------- fallback (only if ws too small): fused naive -------------
__global__ __launch_bounds__(256) void gemm_fallback(const float* __restrict__ A,
                                                     const int* __restrict__ qw,
                                                     const float* __restrict__ sc,
                                                     const float* __restrict__ zr,
                                                     float* __restrict__ C) {
    __shared__ float Ash[16][17];
    __shared__ float Wsh[16][17];
    int tx = threadIdx.x & 15, ty = threadIdx.x >> 4;
    int m = blockIdx.y * 16 + ty;
    int n = blockIdx.x * 16 + tx;
    float s = 0.f;
    for (int k0 = 0; k0 < K_DIM; k0 += 16) {
        Ash[ty][tx] = A[(long)m * K_DIM + k0 + tx];
        {
            int nn = blockIdx.x * 16 + ty;
            int kk = k0 + tx;
            int q = qw[(long)nn * KHALF + (kk >> 1)];
            int nib = (kk & 1) ? ((q >> 4) & 0xF) : (q & 0xF);
            int g = kk >> 7;
            Wsh[ty][tx] = ((float)nib - zr[nn * NG + g]) * sc[nn * NG + g];
        }
        __syncthreads();
#pragma unroll
        for (int kk = 0; kk < 16; ++kk)
            s += Ash[ty][kk] * Wsh[tx][kk];
        __syncthreads();
    }
    C[(long)m * N_DIM + n] = s;
}

extern "C" void kernel_launch(void* const* d_in, const int* in_sizes, int n_in,
                              void* d_out, int out_size, void* d_ws, size_t ws_size,
                              hipStream_t stream) {
    const float* A  = (const float*)d_in[0];
    const int*   qw = (const int*)d_in[1];
    const float* sc = (const float*)d_in[2];
    const float* zr = (const float*)d_in[3];
    float* C = (float*)d_out;

    const size_t needA = (size_t)M_DIM * K_DIM * 2;   // 64 MiB
    const size_t needW = (size_t)N_DIM * K_DIM * 2;   // 32 MiB

    if (ws_size >= needA + needW) {
        __bf16* Ab = (__bf16*)d_ws;
        __bf16* Wb = (__bf16*)((char*)d_ws + needA);
        cvtA_kernel<<<2048, 256, 0, stream>>>(A, Ab, (long)M_DIM * K_DIM / 8);
        deqW_kernel<<<2048, 256, 0, stream>>>(qw, sc, zr, Wb);
        gemm8p<<<(M_DIM / BM) * (N_DIM / BN), 512, 0, stream>>>(Ab, Wb, C);
    } else {
        dim3 g(N_DIM / 16, M_DIM / 16);
        gemm_fallback<<<g, 256, 0, stream>>>(A, qw, sc, zr, C);
    }
}